// Round 4
// baseline (688.839 us; speedup 1.0000x reference)
//
#include <hip/hip_runtime.h>
#include <hip/hip_bf16.h>

// GCN: 5 x (GEMM 64x64 -> CSR gather + bias/ReLU/BN/residual) -> mean-pool -> MLP head.
// R2: hierarchical scan. R3: 4-deep gather unroll + packed csr int2.
// R4: T stored bf16 (gather row = 128B = 1 cacheline, halves gather traffic);
//     8-deep gather unroll. P/residual chain stays fp32 for accuracy.

#define NNODES 100000
#define NEDGES 1000000
#define NGRAPH 64
#define HDIM 64
#define SCAN_CHUNK 1024

typedef unsigned int uint32;
typedef unsigned short ushort16;

__device__ __forceinline__ float bf16_to_f32(ushort16 u) {
    return __uint_as_float(((uint32)u) << 16);
}

// ---------------- zero ----------------
__global__ void zero_kernel(int* __restrict__ p, int n) {
    int i = blockIdx.x * 256 + threadIdx.x;
    if (i < n) p[i] = 0;
}

// ---------------- degree count (in-degree via dst) ----------------
__global__ void count_kernel(const int* __restrict__ ei, int* __restrict__ counts, int E) {
    int e = blockIdx.x * 256 + threadIdx.x;
    if (e < E) atomicAdd(&counts[ei[E + e]], 1);
}

// ---------------- scan level 1 ----------------
__global__ __launch_bounds__(256) void bsum_kernel(const int* __restrict__ counts,
                                                   int* __restrict__ bsums, int N) {
    __shared__ int ws[4];
    int base = blockIdx.x * SCAN_CHUNK + threadIdx.x * 4;
    int s = 0;
    if (base + 3 < N) {
        int4 c = *(const int4*)(counts + base);
        s = c.x + c.y + c.z + c.w;
    } else {
        for (int k = 0; k < 4 && base + k < N; ++k) s += counts[base + k];
    }
    for (int off = 32; off > 0; off >>= 1) s += __shfl_down(s, off, 64);
    int wid = threadIdx.x >> 6;
    if ((threadIdx.x & 63) == 0) ws[wid] = s;
    __syncthreads();
    if (threadIdx.x == 0) bsums[blockIdx.x] = ws[0] + ws[1] + ws[2] + ws[3];
}

// ---------------- scan level 2 ----------------
__global__ __launch_bounds__(256) void bscan_kernel(int* __restrict__ bsums, int nb,
                                                    int* __restrict__ row_ptr, int N, int E) {
    __shared__ int sh[256];
    int t = threadIdx.x;
    sh[t] = (t < nb) ? bsums[t] : 0;
    __syncthreads();
    for (int off = 1; off < 256; off <<= 1) {
        int v = (t >= off) ? sh[t - off] : 0;
        __syncthreads();
        sh[t] += v;
        __syncthreads();
    }
    if (t < nb) bsums[t] = (t == 0) ? 0 : sh[t - 1];
    if (t == 0) row_ptr[N] = E;
}

// ---------------- scan level 3: row_ptr + dinv + cursor ----------------
__global__ __launch_bounds__(256) void scan_apply_kernel(
    const int* __restrict__ counts, const int* __restrict__ bsums,
    int* __restrict__ row_ptr, int* __restrict__ cursor,
    float* __restrict__ dinv, int N) {
    __shared__ int wsum[4];
    int t = threadIdx.x;
    int lane = t & 63, wid = t >> 6;
    int base = blockIdx.x * SCAN_CHUNK + t * 4;
    int c0 = 0, c1 = 0, c2 = 0, c3 = 0;
    if (base + 3 < N) {
        int4 c = *(const int4*)(counts + base);
        c0 = c.x; c1 = c.y; c2 = c.z; c3 = c.w;
    } else if (base < N) {
        c0 = counts[base];
        if (base + 1 < N) c1 = counts[base + 1];
        if (base + 2 < N) c2 = counts[base + 2];
    }
    int tsum = c0 + c1 + c2 + c3;
    int incl = tsum;
    for (int off = 1; off < 64; off <<= 1) {
        int v = __shfl_up(incl, off, 64);
        if (lane >= off) incl += v;
    }
    if (lane == 63) wsum[wid] = incl;
    __syncthreads();
    int woff = 0;
    for (int w = 0; w < wid; ++w) woff += wsum[w];
    int off0 = bsums[blockIdx.x] + woff + (incl - tsum);
    if (base + 3 < N) {
        int4 rp; rp.x = off0; rp.y = off0 + c0; rp.z = off0 + c0 + c1; rp.w = off0 + c0 + c1 + c2;
        *(int4*)(row_ptr + base) = rp;
        *(int4*)(cursor + base) = rp;
        float4 dv;
        dv.x = rsqrtf((float)(c0 + 1)); dv.y = rsqrtf((float)(c1 + 1));
        dv.z = rsqrtf((float)(c2 + 1)); dv.w = rsqrtf((float)(c3 + 1));
        *(float4*)(dinv + base) = dv;
    } else if (base < N) {
        int run = off0;
        int cs[4] = {c0, c1, c2, c3};
        for (int k = 0; k < 4 && base + k < N; ++k) {
            row_ptr[base + k] = run;
            cursor[base + k] = run;
            dinv[base + k] = rsqrtf((float)(cs[k] + 1));
            run += cs[k];
        }
    }
}

// ---------------- fill CSR buckets: packed (src, norm) int2 ----------------
__global__ void fill_kernel(const int* __restrict__ ei, const float* __restrict__ dinv,
                            int* __restrict__ cursor, int2* __restrict__ csr, int E) {
    int e = blockIdx.x * 256 + threadIdx.x;
    if (e < E) {
        int s = ei[e];
        int d = ei[E + e];
        int p = atomicAdd(&cursor[d], 1);
        csr[p] = make_int2(s, __float_as_int(dinv[s] * dinv[d]));
    }
}

// ---------------- GEMM: T(bf16) = A(Nx64,f32) @ W(64x64,f32) ----------------
__global__ __launch_bounds__(256) void gemm64_kernel(const float* __restrict__ A,
                                                     const float* __restrict__ W,
                                                     ushort16* __restrict__ Tb, int N) {
    int row = blockIdx.x * 256 + threadIdx.x;
    if (row >= N) return;
    const float4* arow = (const float4*)(A + (size_t)row * HDIM);
    float acc[HDIM];
#pragma unroll
    for (int j = 0; j < HDIM; ++j) acc[j] = 0.f;
    for (int kk = 0; kk < 16; ++kk) {
        float4 a4 = arow[kk];
        const float* wr = W + kk * 4 * HDIM;
#pragma unroll
        for (int j = 0; j < HDIM; ++j) acc[j] += a4.x * wr[j];
#pragma unroll
        for (int j = 0; j < HDIM; ++j) acc[j] += a4.y * wr[HDIM + j];
#pragma unroll
        for (int j = 0; j < HDIM; ++j) acc[j] += a4.z * wr[2 * HDIM + j];
#pragma unroll
        for (int j = 0; j < HDIM; ++j) acc[j] += a4.w * wr[3 * HDIM + j];
    }
    // pack to bf16 (RNE) and store 128B row as 8 x uint4
    uint32 pk[32];
#pragma unroll
    for (int j = 0; j < 32; ++j) {
        __hip_bfloat16 lo = __float2bfloat16(acc[2 * j]);
        __hip_bfloat16 hi = __float2bfloat16(acc[2 * j + 1]);
        pk[j] = ((uint32)(*(ushort16*)&hi) << 16) | (uint32)(*(ushort16*)&lo);
    }
    uint4* orow = (uint4*)(Tb + (size_t)row * HDIM);
#pragma unroll
    for (int j = 0; j < 8; ++j)
        orow[j] = make_uint4(pk[4 * j], pk[4 * j + 1], pk[4 * j + 2], pk[4 * j + 3]);
}

// ------- gather(bf16) + bias/ReLU/BN/residual (one wave/node, 8 gathers in flight) -----
__global__ __launch_bounds__(256) void aggregate_kernel(
    const ushort16* __restrict__ Tb, const float* __restrict__ dinv,
    const int* __restrict__ row_ptr, const int2* __restrict__ csr,
    const float* __restrict__ bias, const float* __restrict__ gamma,
    const float* __restrict__ beta, const float* __restrict__ mean,
    const float* __restrict__ var,
    float* __restrict__ P, int N, int residual) {
    int node = (blockIdx.x * 256 + threadIdx.x) >> 6;
    int lane = threadIdx.x & 63;
    if (node >= N) return;
    float di = dinv[node];
    float acc = bf16_to_f32(Tb[(size_t)node * HDIM + lane]) * di * di;  // self-loop
    int e0 = row_ptr[node], e1 = row_ptr[node + 1];
    float a0 = 0.f, a1 = 0.f, a2 = 0.f, a3 = 0.f;
    float b0 = 0.f, b1 = 0.f, b2 = 0.f, b3 = 0.f;
    int e = e0;
    for (; e + 8 <= e1; e += 8) {
        int2 c0 = csr[e],     c1 = csr[e + 1], c2 = csr[e + 2], c3 = csr[e + 3];
        int2 c4 = csr[e + 4], c5 = csr[e + 5], c6 = csr[e + 6], c7 = csr[e + 7];
        float t0 = bf16_to_f32(Tb[(size_t)c0.x * HDIM + lane]);
        float t1 = bf16_to_f32(Tb[(size_t)c1.x * HDIM + lane]);
        float t2 = bf16_to_f32(Tb[(size_t)c2.x * HDIM + lane]);
        float t3 = bf16_to_f32(Tb[(size_t)c3.x * HDIM + lane]);
        float t4 = bf16_to_f32(Tb[(size_t)c4.x * HDIM + lane]);
        float t5 = bf16_to_f32(Tb[(size_t)c5.x * HDIM + lane]);
        float t6 = bf16_to_f32(Tb[(size_t)c6.x * HDIM + lane]);
        float t7 = bf16_to_f32(Tb[(size_t)c7.x * HDIM + lane]);
        a0 += t0 * __int_as_float(c0.y);
        a1 += t1 * __int_as_float(c1.y);
        a2 += t2 * __int_as_float(c2.y);
        a3 += t3 * __int_as_float(c3.y);
        b0 += t4 * __int_as_float(c4.y);
        b1 += t5 * __int_as_float(c5.y);
        b2 += t6 * __int_as_float(c6.y);
        b3 += t7 * __int_as_float(c7.y);
    }
    for (; e + 4 <= e1; e += 4) {
        int2 c0 = csr[e], c1 = csr[e + 1], c2 = csr[e + 2], c3 = csr[e + 3];
        float t0 = bf16_to_f32(Tb[(size_t)c0.x * HDIM + lane]);
        float t1 = bf16_to_f32(Tb[(size_t)c1.x * HDIM + lane]);
        float t2 = bf16_to_f32(Tb[(size_t)c2.x * HDIM + lane]);
        float t3 = bf16_to_f32(Tb[(size_t)c3.x * HDIM + lane]);
        a0 += t0 * __int_as_float(c0.y);
        a1 += t1 * __int_as_float(c1.y);
        a2 += t2 * __int_as_float(c2.y);
        a3 += t3 * __int_as_float(c3.y);
    }
    for (; e < e1; ++e) {
        int2 c = csr[e];
        acc += bf16_to_f32(Tb[(size_t)c.x * HDIM + lane]) * __int_as_float(c.y);
    }
    acc += ((a0 + b0) + (a1 + b1)) + ((a2 + b2) + (a3 + b3));
    float v = acc + bias[lane];
    v = fmaxf(v, 0.f);
    v = (v - mean[lane]) * rsqrtf(var[lane] + 1e-5f) * gamma[lane] + beta[lane];
    if (residual) v += P[(size_t)node * HDIM + lane];
    P[(size_t)node * HDIM + lane] = v;
}

// ---------------- mean-pool ----------------
__global__ __launch_bounds__(256) void pool_kernel(const float* __restrict__ P,
                                                   const int* __restrict__ batch,
                                                   float* __restrict__ gsum,
                                                   float* __restrict__ gcnt, int N) {
    int wave = (blockIdx.x * 256 + threadIdx.x) >> 6;
    int lane = threadIdx.x & 63;
    int start = wave * 64;
    if (start >= N) return;
    int end = start + 64; if (end > N) end = N;
    float acc = 0.f;
    int cur = batch[start];
    int cnt = 0;
    for (int i = start; i < end; ++i) {
        int b = batch[i];
        if (b != cur) {
            atomicAdd(&gsum[cur * HDIM + lane], acc);
            if (lane == 0) atomicAdd(&gcnt[cur], (float)cnt);
            cur = b; acc = 0.f; cnt = 0;
        }
        acc += P[(size_t)i * HDIM + lane];
        cnt++;
    }
    atomicAdd(&gsum[cur * HDIM + lane], acc);
    if (lane == 0) atomicAdd(&gcnt[cur], (float)cnt);
}

// ---------------- MLP head (single block) ----------------
__global__ __launch_bounds__(256) void head_kernel(
    const float* __restrict__ gsum, const float* __restrict__ gcnt,
    const float* __restrict__ hW1, const float* __restrict__ hb1,
    const float* __restrict__ hgam, const float* __restrict__ hbet,
    const float* __restrict__ hm, const float* __restrict__ hv,
    const float* __restrict__ hW2, const float* __restrict__ hb2,
    float* __restrict__ out) {
    __shared__ float g[NGRAPH * HDIM];
    __shared__ float h1[NGRAPH * 32];
    int t = threadIdx.x;
    for (int idx = t; idx < NGRAPH * HDIM; idx += 256) {
        int gi = idx >> 6;
        g[idx] = gsum[idx] / fmaxf(gcnt[gi], 1.f);
    }
    __syncthreads();
    for (int idx = t; idx < NGRAPH * 32; idx += 256) {
        int gi = idx >> 5, j = idx & 31;
        float s = hb1[j];
#pragma unroll
        for (int f = 0; f < HDIM; ++f) s += g[gi * HDIM + f] * hW1[f * 32 + j];
        s = fmaxf(s, 0.f);
        s = (s - hm[j]) * rsqrtf(hv[j] + 1e-5f) * hgam[j] + hbet[j];
        h1[idx] = s;
    }
    __syncthreads();
    if (t < NGRAPH) {
        float s = hb2[0];
#pragma unroll
        for (int j = 0; j < 32; ++j) s += h1[t * 32 + j] * hW2[j];
        out[t] = s;
    }
}

static inline size_t align_up(size_t x) { return (x + 255) & ~(size_t)255; }

extern "C" void kernel_launch(void* const* d_in, const int* in_sizes, int n_in,
                              void* d_out, int out_size, void* d_ws, size_t ws_size,
                              hipStream_t stream) {
    const float* x    = (const float*)d_in[0];
    const int*   ei   = (const int*)d_in[1];
    const int*   batch= (const int*)d_in[2];
    const float* Wc   = (const float*)d_in[3];
    const float* bc   = (const float*)d_in[4];
    const float* bng  = (const float*)d_in[5];
    const float* bnb  = (const float*)d_in[6];
    const float* bnm  = (const float*)d_in[7];
    const float* bnv  = (const float*)d_in[8];
    const float* hW1  = (const float*)d_in[9];
    const float* hb1  = (const float*)d_in[10];
    const float* hgam = (const float*)d_in[11];
    const float* hbet = (const float*)d_in[12];
    const float* hm   = (const float*)d_in[13];
    const float* hv   = (const float*)d_in[14];
    const float* hW2  = (const float*)d_in[15];
    const float* hb2  = (const float*)d_in[16];
    float* out = (float*)d_out;

    const int N = in_sizes[0] / HDIM;   // 100000
    const int E = in_sizes[1] / 2;      // 1000000

    // ---- workspace carve (all 256B aligned) ----
    char* ws = (char*)d_ws;
    size_t off = 0;
    float*    P  = (float*)(ws + off);    off += align_up((size_t)N * HDIM * 4);
    ushort16* Tb = (ushort16*)(ws + off); off += align_up((size_t)N * HDIM * 2);
    int*   counts = (int*)(ws + off);
    float* gsum = (float*)(ws + off + (size_t)N * 4);
    float* gcnt = (float*)(ws + off + (size_t)N * 4 + NGRAPH * HDIM * 4);
    int zero_n = N + NGRAPH * HDIM + NGRAPH;
    off += align_up((size_t)zero_n * 4);
    int*   row_ptr = (int*)(ws + off);    off += align_up((size_t)(N + 1) * 4);
    int*   cursor  = (int*)(ws + off);    off += align_up((size_t)N * 4);
    float* dinv    = (float*)(ws + off);  off += align_up((size_t)N * 4);
    int*   bsums   = (int*)(ws + off);    off += align_up(256 * 4);
    int2*  csr     = (int2*)(ws + off);   off += align_up((size_t)E * 8);

    int gE = (E + 255) / 256;
    int gN = (N + 255) / 256;
    int nScanBlocks = (N + SCAN_CHUNK - 1) / SCAN_CHUNK;

    // ---- build degree + CSR ----
    zero_kernel<<<(zero_n + 255) / 256, 256, 0, stream>>>(counts, zero_n);
    count_kernel<<<gE, 256, 0, stream>>>(ei, counts, E);
    bsum_kernel<<<nScanBlocks, 256, 0, stream>>>(counts, bsums, N);
    bscan_kernel<<<1, 256, 0, stream>>>(bsums, nScanBlocks, row_ptr, N, E);
    scan_apply_kernel<<<nScanBlocks, 256, 0, stream>>>(counts, bsums, row_ptr, cursor, dinv, N);
    fill_kernel<<<gE, 256, 0, stream>>>(ei, dinv, cursor, csr, E);

    // ---- 5 GCN layers ----
    int aggBlocks = (N + 3) / 4;
    for (int l = 0; l < 5; ++l) {
        const float* in = (l == 0) ? x : P;
        gemm64_kernel<<<gN, 256, 0, stream>>>(in, Wc + (size_t)l * HDIM * HDIM, Tb, N);
        aggregate_kernel<<<aggBlocks, 256, 0, stream>>>(
            Tb, dinv, row_ptr, csr,
            bc + l * HDIM, bng + l * HDIM, bnb + l * HDIM, bnm + l * HDIM, bnv + l * HDIM,
            P, N, (l > 0) ? 1 : 0);
    }

    // ---- pool + head ----
    int poolBlocks = (N + 255) / 256;
    pool_kernel<<<poolBlocks, 256, 0, stream>>>(P, batch, gsum, gcnt, N);
    head_kernel<<<1, 256, 0, stream>>>(gsum, gcnt, hW1, hb1, hgam, hbet, hm, hv, hW2, hb2, out);
}

// Round 5
// 650.352 us; speedup vs baseline: 1.0592x; 1.0592x over previous
//
#include <hip/hip_runtime.h>
#include <hip/hip_bf16.h>

// GCN: 5 x (GEMM 64x64 -> CSR gather + bias/ReLU/BN/residual) -> mean-pool -> MLP head.
// R2: hierarchical scan. R3: unrolled gather. R4: bf16 T (128B rows).
// R5: norm folded into GEMM (T' = dinv*A*W)  -> csr is src-only (4B/edge);
//     buckets padded to x16 with sentinel row N (Tb[N]=0) -> branch-free 16-wide
//     gather batches, 16 loads in flight; pad_kernel writes sentinels.

#define NNODES 100000
#define NEDGES 1000000
#define NGRAPH 64
#define HDIM 64
#define SCAN_CHUNK 1024
#define PADM 16   // bucket pad multiple

typedef unsigned int uint32;
typedef unsigned short ushort16;

__device__ __forceinline__ float bf16_to_f32(ushort16 u) {
    return __uint_as_float(((uint32)u) << 16);
}
__device__ __forceinline__ uint32 pack_bf16x2(float lo, float hi) {
    __hip_bfloat16 l = __float2bfloat16(lo);
    __hip_bfloat16 h = __float2bfloat16(hi);
    return ((uint32)(*(ushort16*)&h) << 16) | (uint32)(*(ushort16*)&l);
}
__device__ __forceinline__ int padded(int c) { return (c + PADM - 1) & ~(PADM - 1); }

// ---------------- zero ----------------
__global__ void zero_kernel(int* __restrict__ p, int n) {
    int i = blockIdx.x * 256 + threadIdx.x;
    if (i < n) p[i] = 0;
}

// ---------------- degree count (in-degree via dst) ----------------
__global__ void count_kernel(const int* __restrict__ ei, int* __restrict__ counts, int E) {
    int e = blockIdx.x * 256 + threadIdx.x;
    if (e < E) atomicAdd(&counts[ei[E + e]], 1);
}

// ---------------- scan level 1: per-block partial sums of PADDED counts ---------------
__global__ __launch_bounds__(256) void bsum_kernel(const int* __restrict__ counts,
                                                   int* __restrict__ bsums, int N) {
    __shared__ int ws[4];
    int base = blockIdx.x * SCAN_CHUNK + threadIdx.x * 4;
    int s = 0;
    if (base + 3 < N) {
        int4 c = *(const int4*)(counts + base);
        s = padded(c.x) + padded(c.y) + padded(c.z) + padded(c.w);
    } else {
        for (int k = 0; k < 4 && base + k < N; ++k) s += padded(counts[base + k]);
    }
    for (int off = 32; off > 0; off >>= 1) s += __shfl_down(s, off, 64);
    int wid = threadIdx.x >> 6;
    if ((threadIdx.x & 63) == 0) ws[wid] = s;
    __syncthreads();
    if (threadIdx.x == 0) bsums[blockIdx.x] = ws[0] + ws[1] + ws[2] + ws[3];
}

// ---------------- scan level 2 ----------------
__global__ __launch_bounds__(256) void bscan_kernel(int* __restrict__ bsums, int nb,
                                                    int* __restrict__ row_ptr, int N) {
    __shared__ int sh[256];
    int t = threadIdx.x;
    sh[t] = (t < nb) ? bsums[t] : 0;
    __syncthreads();
    for (int off = 1; off < 256; off <<= 1) {
        int v = (t >= off) ? sh[t - off] : 0;
        __syncthreads();
        sh[t] += v;
        __syncthreads();
    }
    if (t < nb) bsums[t] = (t == 0) ? 0 : sh[t - 1];
    if (t == 255) row_ptr[N] = sh[255];   // total padded entries
}

// ---------------- scan level 3: row_ptr(padded) + dinv + cursor ----------------
__global__ __launch_bounds__(256) void scan_apply_kernel(
    const int* __restrict__ counts, const int* __restrict__ bsums,
    int* __restrict__ row_ptr, int* __restrict__ cursor,
    float* __restrict__ dinv, int N) {
    __shared__ int wsum[4];
    int t = threadIdx.x;
    int lane = t & 63, wid = t >> 6;
    int base = blockIdx.x * SCAN_CHUNK + t * 4;
    int c0 = 0, c1 = 0, c2 = 0, c3 = 0;
    if (base + 3 < N) {
        int4 c = *(const int4*)(counts + base);
        c0 = c.x; c1 = c.y; c2 = c.z; c3 = c.w;
    } else if (base < N) {
        c0 = counts[base];
        if (base + 1 < N) c1 = counts[base + 1];
        if (base + 2 < N) c2 = counts[base + 2];
    }
    int p0 = padded(c0), p1 = padded(c1), p2 = padded(c2), p3 = padded(c3);
    int tsum = p0 + p1 + p2 + p3;
    int incl = tsum;
    for (int off = 1; off < 64; off <<= 1) {
        int v = __shfl_up(incl, off, 64);
        if (lane >= off) incl += v;
    }
    if (lane == 63) wsum[wid] = incl;
    __syncthreads();
    int woff = 0;
    for (int w = 0; w < wid; ++w) woff += wsum[w];
    int off0 = bsums[blockIdx.x] + woff + (incl - tsum);
    if (base + 3 < N) {
        int4 rp; rp.x = off0; rp.y = off0 + p0; rp.z = off0 + p0 + p1; rp.w = off0 + p0 + p1 + p2;
        *(int4*)(row_ptr + base) = rp;
        *(int4*)(cursor + base) = rp;
        float4 dv;
        dv.x = rsqrtf((float)(c0 + 1)); dv.y = rsqrtf((float)(c1 + 1));
        dv.z = rsqrtf((float)(c2 + 1)); dv.w = rsqrtf((float)(c3 + 1));
        *(float4*)(dinv + base) = dv;
    } else if (base < N) {
        int run = off0;
        int cs[4] = {c0, c1, c2, c3};
        for (int k = 0; k < 4 && base + k < N; ++k) {
            row_ptr[base + k] = run;
            cursor[base + k] = run;
            dinv[base + k] = rsqrtf((float)(cs[k] + 1));
            run += padded(cs[k]);
        }
    }
}

// ---------------- pad buckets with sentinel N ----------------
__global__ void pad_kernel(const int* __restrict__ counts, const int* __restrict__ row_ptr,
                           int* __restrict__ csr, int N) {
    int i = blockIdx.x * 256 + threadIdx.x;
    if (i >= N) return;
    int s = row_ptr[i] + counts[i];
    int e = row_ptr[i + 1];
    for (int p = s; p < e; ++p) csr[p] = N;   // sentinel -> zero row
}

// ---------------- fill CSR buckets: src only ----------------
__global__ void fill_kernel(const int* __restrict__ ei, int* __restrict__ cursor,
                            int* __restrict__ csr, int E) {
    int e = blockIdx.x * 256 + threadIdx.x;
    if (e < E) {
        int s = ei[e];
        int d = ei[E + e];
        int p = atomicAdd(&cursor[d], 1);
        csr[p] = s;
    }
}

// ---------------- GEMM: T'(bf16) = dinv[row] * (A(Nx64,f32) @ W(64x64,f32)) -------------
__global__ __launch_bounds__(256) void gemm64_kernel(const float* __restrict__ A,
                                                     const float* __restrict__ W,
                                                     const float* __restrict__ dinv,
                                                     ushort16* __restrict__ Tb, int N) {
    int row = blockIdx.x * 256 + threadIdx.x;
    if (row >= N) return;
    const float4* arow = (const float4*)(A + (size_t)row * HDIM);
    float acc[HDIM];
#pragma unroll
    for (int j = 0; j < HDIM; ++j) acc[j] = 0.f;
    for (int kk = 0; kk < 16; ++kk) {
        float4 a4 = arow[kk];
        const float* wr = W + kk * 4 * HDIM;
#pragma unroll
        for (int j = 0; j < HDIM; ++j) acc[j] += a4.x * wr[j];
#pragma unroll
        for (int j = 0; j < HDIM; ++j) acc[j] += a4.y * wr[HDIM + j];
#pragma unroll
        for (int j = 0; j < HDIM; ++j) acc[j] += a4.z * wr[2 * HDIM + j];
#pragma unroll
        for (int j = 0; j < HDIM; ++j) acc[j] += a4.w * wr[3 * HDIM + j];
    }
    float di = dinv[row];
    uint4* orow = (uint4*)(Tb + (size_t)row * HDIM);
#pragma unroll
    for (int j = 0; j < 8; ++j) {
        uint4 o;
        o.x = pack_bf16x2(acc[8 * j]     * di, acc[8 * j + 1] * di);
        o.y = pack_bf16x2(acc[8 * j + 2] * di, acc[8 * j + 3] * di);
        o.z = pack_bf16x2(acc[8 * j + 4] * di, acc[8 * j + 5] * di);
        o.w = pack_bf16x2(acc[8 * j + 6] * di, acc[8 * j + 7] * di);
        orow[j] = o;
    }
}

// ------- gather(bf16) + bias/ReLU/BN/residual: 16-wide branch-free batches ------------
__global__ __launch_bounds__(256) void aggregate_kernel(
    const ushort16* __restrict__ Tb, const float* __restrict__ dinv,
    const int* __restrict__ row_ptr, const int* __restrict__ csr,
    const float* __restrict__ bias, const float* __restrict__ gamma,
    const float* __restrict__ beta, const float* __restrict__ mean,
    const float* __restrict__ var,
    float* __restrict__ P, int N, int residual) {
    int node = (blockIdx.x * 256 + threadIdx.x) >> 6;
    int lane = threadIdx.x & 63;
    if (node >= N) return;
    int e = row_ptr[node], e1 = row_ptr[node + 1];
    float a0 = bf16_to_f32(Tb[(size_t)node * HDIM + lane]);  // self-loop term
    float a1 = 0.f, a2 = 0.f, a3 = 0.f;
    for (; e < e1; e += 16) {
        int4 s0 = *(const int4*)(csr + e);
        int4 s1 = *(const int4*)(csr + e + 4);
        int4 s2 = *(const int4*)(csr + e + 8);
        int4 s3 = *(const int4*)(csr + e + 12);
        float t0  = bf16_to_f32(Tb[(size_t)s0.x * HDIM + lane]);
        float t1  = bf16_to_f32(Tb[(size_t)s0.y * HDIM + lane]);
        float t2  = bf16_to_f32(Tb[(size_t)s0.z * HDIM + lane]);
        float t3  = bf16_to_f32(Tb[(size_t)s0.w * HDIM + lane]);
        float t4  = bf16_to_f32(Tb[(size_t)s1.x * HDIM + lane]);
        float t5  = bf16_to_f32(Tb[(size_t)s1.y * HDIM + lane]);
        float t6  = bf16_to_f32(Tb[(size_t)s1.z * HDIM + lane]);
        float t7  = bf16_to_f32(Tb[(size_t)s1.w * HDIM + lane]);
        float t8  = bf16_to_f32(Tb[(size_t)s2.x * HDIM + lane]);
        float t9  = bf16_to_f32(Tb[(size_t)s2.y * HDIM + lane]);
        float t10 = bf16_to_f32(Tb[(size_t)s2.z * HDIM + lane]);
        float t11 = bf16_to_f32(Tb[(size_t)s2.w * HDIM + lane]);
        float t12 = bf16_to_f32(Tb[(size_t)s3.x * HDIM + lane]);
        float t13 = bf16_to_f32(Tb[(size_t)s3.y * HDIM + lane]);
        float t14 = bf16_to_f32(Tb[(size_t)s3.z * HDIM + lane]);
        float t15 = bf16_to_f32(Tb[(size_t)s3.w * HDIM + lane]);
        a0 += t0 + t4;
        a1 += t1 + t5;
        a2 += t2 + t6;
        a3 += t3 + t7;
        a0 += t8 + t12;
        a1 += t9 + t13;
        a2 += t10 + t14;
        a3 += t11 + t15;
    }
    float acc = (a0 + a1) + (a2 + a3);
    float v = acc * dinv[node] + bias[lane];
    v = fmaxf(v, 0.f);
    v = (v - mean[lane]) * rsqrtf(var[lane] + 1e-5f) * gamma[lane] + beta[lane];
    if (residual) v += P[(size_t)node * HDIM + lane];
    P[(size_t)node * HDIM + lane] = v;
}

// ---------------- mean-pool ----------------
__global__ __launch_bounds__(256) void pool_kernel(const float* __restrict__ P,
                                                   const int* __restrict__ batch,
                                                   float* __restrict__ gsum,
                                                   float* __restrict__ gcnt, int N) {
    int wave = (blockIdx.x * 256 + threadIdx.x) >> 6;
    int lane = threadIdx.x & 63;
    int start = wave * 64;
    if (start >= N) return;
    int end = start + 64; if (end > N) end = N;
    float acc = 0.f;
    int cur = batch[start];
    int cnt = 0;
    for (int i = start; i < end; ++i) {
        int b = batch[i];
        if (b != cur) {
            atomicAdd(&gsum[cur * HDIM + lane], acc);
            if (lane == 0) atomicAdd(&gcnt[cur], (float)cnt);
            cur = b; acc = 0.f; cnt = 0;
        }
        acc += P[(size_t)i * HDIM + lane];
        cnt++;
    }
    atomicAdd(&gsum[cur * HDIM + lane], acc);
    if (lane == 0) atomicAdd(&gcnt[cur], (float)cnt);
}

// ---------------- MLP head (single block) ----------------
__global__ __launch_bounds__(256) void head_kernel(
    const float* __restrict__ gsum, const float* __restrict__ gcnt,
    const float* __restrict__ hW1, const float* __restrict__ hb1,
    const float* __restrict__ hgam, const float* __restrict__ hbet,
    const float* __restrict__ hm, const float* __restrict__ hv,
    const float* __restrict__ hW2, const float* __restrict__ hb2,
    float* __restrict__ out) {
    __shared__ float g[NGRAPH * HDIM];
    __shared__ float h1[NGRAPH * 32];
    int t = threadIdx.x;
    for (int idx = t; idx < NGRAPH * HDIM; idx += 256) {
        int gi = idx >> 6;
        g[idx] = gsum[idx] / fmaxf(gcnt[gi], 1.f);
    }
    __syncthreads();
    for (int idx = t; idx < NGRAPH * 32; idx += 256) {
        int gi = idx >> 5, j = idx & 31;
        float s = hb1[j];
#pragma unroll
        for (int f = 0; f < HDIM; ++f) s += g[gi * HDIM + f] * hW1[f * 32 + j];
        s = fmaxf(s, 0.f);
        s = (s - hm[j]) * rsqrtf(hv[j] + 1e-5f) * hgam[j] + hbet[j];
        h1[idx] = s;
    }
    __syncthreads();
    if (t < NGRAPH) {
        float s = hb2[0];
#pragma unroll
        for (int j = 0; j < 32; ++j) s += h1[t * 32 + j] * hW2[j];
        out[t] = s;
    }
}

static inline size_t align_up(size_t x) { return (x + 255) & ~(size_t)255; }

extern "C" void kernel_launch(void* const* d_in, const int* in_sizes, int n_in,
                              void* d_out, int out_size, void* d_ws, size_t ws_size,
                              hipStream_t stream) {
    const float* x    = (const float*)d_in[0];
    const int*   ei   = (const int*)d_in[1];
    const int*   batch= (const int*)d_in[2];
    const float* Wc   = (const float*)d_in[3];
    const float* bc   = (const float*)d_in[4];
    const float* bng  = (const float*)d_in[5];
    const float* bnb  = (const float*)d_in[6];
    const float* bnm  = (const float*)d_in[7];
    const float* bnv  = (const float*)d_in[8];
    const float* hW1  = (const float*)d_in[9];
    const float* hb1  = (const float*)d_in[10];
    const float* hgam = (const float*)d_in[11];
    const float* hbet = (const float*)d_in[12];
    const float* hm   = (const float*)d_in[13];
    const float* hv   = (const float*)d_in[14];
    const float* hW2  = (const float*)d_in[15];
    const float* hb2  = (const float*)d_in[16];
    float* out = (float*)d_out;

    const int N = in_sizes[0] / HDIM;   // 100000
    const int E = in_sizes[1] / 2;      // 1000000

    // ---- workspace carve (all 256B aligned) ----
    char* ws = (char*)d_ws;
    size_t off = 0;
    float*    P  = (float*)(ws + off);    off += align_up((size_t)N * HDIM * 4);
    ushort16* Tb = (ushort16*)(ws + off); off += align_up((size_t)(N + 1) * HDIM * 2); // +1 sentinel row
    int*   counts = (int*)(ws + off);
    float* gsum = (float*)(ws + off + (size_t)N * 4);
    float* gcnt = (float*)(ws + off + (size_t)N * 4 + NGRAPH * HDIM * 4);
    int zero_n = N + NGRAPH * HDIM + NGRAPH;
    off += align_up((size_t)zero_n * 4);
    int*   row_ptr = (int*)(ws + off);    off += align_up((size_t)(N + 1) * 4);
    int*   cursor  = (int*)(ws + off);    off += align_up((size_t)N * 4);
    float* dinv    = (float*)(ws + off);  off += align_up((size_t)N * 4);
    int*   bsums   = (int*)(ws + off);    off += align_up(256 * 4);
    int*   csr     = (int*)(ws + off);    off += align_up(((size_t)E + (size_t)(PADM - 1) * N) * 4);

    int gE = (E + 255) / 256;
    int gN = (N + 255) / 256;
    int nScanBlocks = (N + SCAN_CHUNK - 1) / SCAN_CHUNK;

    // ---- build degree + padded CSR ----
    zero_kernel<<<(zero_n + 255) / 256, 256, 0, stream>>>(counts, zero_n);
    zero_kernel<<<1, 256, 0, stream>>>((int*)(Tb + (size_t)N * HDIM), 32);  // sentinel row = 0
    count_kernel<<<gE, 256, 0, stream>>>(ei, counts, E);
    bsum_kernel<<<nScanBlocks, 256, 0, stream>>>(counts, bsums, N);
    bscan_kernel<<<1, 256, 0, stream>>>(bsums, nScanBlocks, row_ptr, N);
    scan_apply_kernel<<<nScanBlocks, 256, 0, stream>>>(counts, bsums, row_ptr, cursor, dinv, N);
    pad_kernel<<<gN, 256, 0, stream>>>(counts, row_ptr, csr, N);
    fill_kernel<<<gE, 256, 0, stream>>>(ei, cursor, csr, E);

    // ---- 5 GCN layers ----
    int aggBlocks = (N + 3) / 4;
    for (int l = 0; l < 5; ++l) {
        const float* in = (l == 0) ? x : P;
        gemm64_kernel<<<gN, 256, 0, stream>>>(in, Wc + (size_t)l * HDIM * HDIM, dinv, Tb, N);
        aggregate_kernel<<<aggBlocks, 256, 0, stream>>>(
            Tb, dinv, row_ptr, csr,
            bc + l * HDIM, bng + l * HDIM, bnb + l * HDIM, bnm + l * HDIM, bnv + l * HDIM,
            P, N, (l > 0) ? 1 : 0);
    }

    // ---- pool + head ----
    int poolBlocks = (N + 255) / 256;
    pool_kernel<<<poolBlocks, 256, 0, stream>>>(P, batch, gsum, gcnt, N);
    head_kernel<<<1, 256, 0, stream>>>(gsum, gcnt, hW1, hb1, hgam, hbet, hm, hv, hW2, hb2, out);
}

// Round 6
// 584.716 us; speedup vs baseline: 1.1781x; 1.1123x over previous
//
#include <hip/hip_runtime.h>
#include <hip/hip_bf16.h>

// GCN: 5 x (GEMM 64x64 -> CSR gather + bias/ReLU/BN/residual) -> mean-pool -> MLP head.
// R2: hierarchical scan. R3: unrolled gather. R4: bf16 T. R5: norm folded into GEMM,
//     padded branch-free 16-wide gather.
// R6: CSR build via 2-phase bucket partition (bucket = 256 nodes):
//     A1 LDS bucket-hist -> scan -> A2 partition (dense runs) ->
//     B0 per-bucket LDS degree (dense counts, no global atomics) ->
//     B1 per-bucket LDS counting-sort scatter + fused sentinel padding.
//     Removes 1M-scale global atomics and 16x scatter write amplification.

#define NNODES 100000
#define NEDGES 1000000
#define NGRAPH 64
#define HDIM 64
#define SCAN_CHUNK 1024
#define PADM 16      // bucket pad multiple for aggregate's 16-wide batches
#define EPB 4096     // edges per block in partition phases

typedef unsigned int uint32;
typedef unsigned short ushort16;

__device__ __forceinline__ float bf16_to_f32(ushort16 u) {
    return __uint_as_float(((uint32)u) << 16);
}
__device__ __forceinline__ uint32 pack_bf16x2(float lo, float hi) {
    __hip_bfloat16 l = __float2bfloat16(lo);
    __hip_bfloat16 h = __float2bfloat16(hi);
    return ((uint32)(*(ushort16*)&h) << 16) | (uint32)(*(ushort16*)&l);
}
__device__ __forceinline__ int padded(int c) { return (c + PADM - 1) & ~(PADM - 1); }

// ---------------- zero ----------------
__global__ void zero_kernel(int* __restrict__ p, int n) {
    int i = blockIdx.x * 256 + threadIdx.x;
    if (i < n) p[i] = 0;
}

// ---------------- A1: bucket histogram (bucket = dst>>8) ----------------
__global__ __launch_bounds__(256) void bucket_hist_kernel(const int* __restrict__ ei,
                                                          int* __restrict__ bhist,
                                                          int E, int nbuck) {
    __shared__ int h[512];
    for (int i = threadIdx.x; i < nbuck; i += 256) h[i] = 0;
    __syncthreads();
    int base = blockIdx.x * EPB;
    int end = base + EPB; if (end > E) end = E;
    for (int e = base + threadIdx.x; e < end; e += 256)
        atomicAdd(&h[ei[E + e] >> 8], 1);
    __syncthreads();
    for (int i = threadIdx.x; i < nbuck; i += 256)
        if (h[i]) atomicAdd(&bhist[i], h[i]);
}

// ---------------- bucket scan: bases + cursors ----------------
__global__ __launch_bounds__(512) void bucket_scan_kernel(const int* __restrict__ bhist,
                                                          int* __restrict__ bbase,
                                                          int* __restrict__ bcursor,
                                                          int nbuck) {
    __shared__ int sh[512];
    int t = threadIdx.x;
    sh[t] = (t < nbuck) ? bhist[t] : 0;
    __syncthreads();
    for (int off = 1; off < 512; off <<= 1) {
        int v = (t >= off) ? sh[t - off] : 0;
        __syncthreads();
        sh[t] += v;
        __syncthreads();
    }
    int ex = (t == 0) ? 0 : sh[t - 1];
    if (t < nbuck) { bbase[t] = ex; bcursor[t] = ex; }
    if (t == nbuck) bbase[t] = sh[nbuck - 1];   // = E
}

// ---------------- A2: partition edges into bucket-contiguous (src,dst) ----------------
__global__ __launch_bounds__(256) void partition_kernel(const int* __restrict__ ei,
                                                        int* __restrict__ bcursor,
                                                        int2* __restrict__ barr,
                                                        int E, int nbuck) {
    __shared__ int h[512];
    __shared__ int lbase[512];
    for (int i = threadIdx.x; i < nbuck; i += 256) h[i] = 0;
    __syncthreads();
    int base = blockIdx.x * EPB;
    int end = base + EPB; if (end > E) end = E;
    for (int e = base + threadIdx.x; e < end; e += 256)
        atomicAdd(&h[ei[E + e] >> 8], 1);
    __syncthreads();
    for (int i = threadIdx.x; i < nbuck; i += 256) {
        int c = h[i];
        lbase[i] = c ? atomicAdd(&bcursor[i], c) : 0;
        h[i] = 0;   // reuse as local cursor
    }
    __syncthreads();
    for (int e = base + threadIdx.x; e < end; e += 256) {
        int s = ei[e];
        int d = ei[E + e];
        int b = d >> 8;
        int r = atomicAdd(&h[b], 1);
        barr[lbase[b] + r] = make_int2(s, d);
    }
}

// ---------------- B0: per-bucket node degrees (dense write, LDS hist) ------------------
__global__ __launch_bounds__(256) void degree_kernel(const int2* __restrict__ barr,
                                                     const int* __restrict__ bbase,
                                                     int* __restrict__ counts, int N) {
    __shared__ int h[256];
    h[threadIdx.x] = 0;
    __syncthreads();
    int b = blockIdx.x;
    int s0 = bbase[b], s1 = bbase[b + 1];
    for (int e = s0 + threadIdx.x; e < s1; e += 256)
        atomicAdd(&h[barr[e].y & 255], 1);
    __syncthreads();
    int node = (b << 8) + threadIdx.x;
    if (node < N) counts[node] = h[threadIdx.x];
}

// ---------------- scan level 1: per-block partial sums of PADDED counts ---------------
__global__ __launch_bounds__(256) void bsum_kernel(const int* __restrict__ counts,
                                                   int* __restrict__ bsums, int N) {
    __shared__ int ws[4];
    int base = blockIdx.x * SCAN_CHUNK + threadIdx.x * 4;
    int s = 0;
    if (base + 3 < N) {
        int4 c = *(const int4*)(counts + base);
        s = padded(c.x) + padded(c.y) + padded(c.z) + padded(c.w);
    } else {
        for (int k = 0; k < 4 && base + k < N; ++k) s += padded(counts[base + k]);
    }
    for (int off = 32; off > 0; off >>= 1) s += __shfl_down(s, off, 64);
    int wid = threadIdx.x >> 6;
    if ((threadIdx.x & 63) == 0) ws[wid] = s;
    __syncthreads();
    if (threadIdx.x == 0) bsums[blockIdx.x] = ws[0] + ws[1] + ws[2] + ws[3];
}

// ---------------- scan level 2 ----------------
__global__ __launch_bounds__(256) void bscan_kernel(int* __restrict__ bsums, int nb,
                                                    int* __restrict__ row_ptr, int N) {
    __shared__ int sh[256];
    int t = threadIdx.x;
    sh[t] = (t < nb) ? bsums[t] : 0;
    __syncthreads();
    for (int off = 1; off < 256; off <<= 1) {
        int v = (t >= off) ? sh[t - off] : 0;
        __syncthreads();
        sh[t] += v;
        __syncthreads();
    }
    if (t < nb) bsums[t] = (t == 0) ? 0 : sh[t - 1];
    if (t == 255) row_ptr[N] = sh[255];   // total padded entries
}

// ---------------- scan level 3: row_ptr (padded) + dinv ----------------
__global__ __launch_bounds__(256) void scan_apply_kernel(
    const int* __restrict__ counts, const int* __restrict__ bsums,
    int* __restrict__ row_ptr, float* __restrict__ dinv, int N) {
    __shared__ int wsum[4];
    int t = threadIdx.x;
    int lane = t & 63, wid = t >> 6;
    int base = blockIdx.x * SCAN_CHUNK + t * 4;
    int c0 = 0, c1 = 0, c2 = 0, c3 = 0;
    if (base + 3 < N) {
        int4 c = *(const int4*)(counts + base);
        c0 = c.x; c1 = c.y; c2 = c.z; c3 = c.w;
    } else if (base < N) {
        c0 = counts[base];
        if (base + 1 < N) c1 = counts[base + 1];
        if (base + 2 < N) c2 = counts[base + 2];
    }
    int p0 = padded(c0), p1 = padded(c1), p2 = padded(c2), p3 = padded(c3);
    int tsum = p0 + p1 + p2 + p3;
    int incl = tsum;
    for (int off = 1; off < 64; off <<= 1) {
        int v = __shfl_up(incl, off, 64);
        if (lane >= off) incl += v;
    }
    if (lane == 63) wsum[wid] = incl;
    __syncthreads();
    int woff = 0;
    for (int w = 0; w < wid; ++w) woff += wsum[w];
    int off0 = bsums[blockIdx.x] + woff + (incl - tsum);
    if (base + 3 < N) {
        int4 rp; rp.x = off0; rp.y = off0 + p0; rp.z = off0 + p0 + p1; rp.w = off0 + p0 + p1 + p2;
        *(int4*)(row_ptr + base) = rp;
        float4 dv;
        dv.x = rsqrtf((float)(c0 + 1)); dv.y = rsqrtf((float)(c1 + 1));
        dv.z = rsqrtf((float)(c2 + 1)); dv.w = rsqrtf((float)(c3 + 1));
        *(float4*)(dinv + base) = dv;
    } else if (base < N) {
        int run = off0;
        int cs[4] = {c0, c1, c2, c3};
        for (int k = 0; k < 4 && base + k < N; ++k) {
            row_ptr[base + k] = run;
            dinv[base + k] = rsqrtf((float)(cs[k] + 1));
            run += padded(cs[k]);
        }
    }
}

// ---------------- B1: per-bucket counting-sort into csr + sentinel padding -------------
__global__ __launch_bounds__(256) void fill_kernel(const int2* __restrict__ barr,
                                                   const int* __restrict__ bbase,
                                                   const int* __restrict__ row_ptr,
                                                   int* __restrict__ csr, int N) {
    __shared__ int rbase[257];
    __shared__ int cur[256];
    int b = blockIdx.x;
    int n0 = b << 8;
    int nn = N - n0; if (nn > 256) nn = 256;
    int t = threadIdx.x;
    if (t < nn) { rbase[t] = row_ptr[n0 + t]; cur[t] = 0; }
    if (t == 0) rbase[nn] = row_ptr[n0 + nn];
    __syncthreads();
    int s0 = bbase[b], s1 = bbase[b + 1];
    for (int e = s0 + t; e < s1; e += 256) {
        int2 ed = barr[e];
        int d = ed.y & 255;
        int r = atomicAdd(&cur[d], 1);
        csr[rbase[d] + r] = ed.x;
    }
    __syncthreads();
    if (t < nn) {
        int p = rbase[t] + cur[t];
        int pe = rbase[t + 1];
        for (; p < pe; ++p) csr[p] = N;   // sentinel -> zero row Tb[N]
    }
}

// ---------------- GEMM: T'(bf16) = dinv[row] * (A(Nx64,f32) @ W(64x64,f32)) -------------
__global__ __launch_bounds__(256) void gemm64_kernel(const float* __restrict__ A,
                                                     const float* __restrict__ W,
                                                     const float* __restrict__ dinv,
                                                     ushort16* __restrict__ Tb, int N) {
    int row = blockIdx.x * 256 + threadIdx.x;
    if (row >= N) return;
    const float4* arow = (const float4*)(A + (size_t)row * HDIM);
    float acc[HDIM];
#pragma unroll
    for (int j = 0; j < HDIM; ++j) acc[j] = 0.f;
    for (int kk = 0; kk < 16; ++kk) {
        float4 a4 = arow[kk];
        const float* wr = W + kk * 4 * HDIM;
#pragma unroll
        for (int j = 0; j < HDIM; ++j) acc[j] += a4.x * wr[j];
#pragma unroll
        for (int j = 0; j < HDIM; ++j) acc[j] += a4.y * wr[HDIM + j];
#pragma unroll
        for (int j = 0; j < HDIM; ++j) acc[j] += a4.z * wr[2 * HDIM + j];
#pragma unroll
        for (int j = 0; j < HDIM; ++j) acc[j] += a4.w * wr[3 * HDIM + j];
    }
    float di = dinv[row];
    uint4* orow = (uint4*)(Tb + (size_t)row * HDIM);
#pragma unroll
    for (int j = 0; j < 8; ++j) {
        uint4 o;
        o.x = pack_bf16x2(acc[8 * j]     * di, acc[8 * j + 1] * di);
        o.y = pack_bf16x2(acc[8 * j + 2] * di, acc[8 * j + 3] * di);
        o.z = pack_bf16x2(acc[8 * j + 4] * di, acc[8 * j + 5] * di);
        o.w = pack_bf16x2(acc[8 * j + 6] * di, acc[8 * j + 7] * di);
        orow[j] = o;
    }
}

// ------- gather(bf16) + bias/ReLU/BN/residual: 16-wide branch-free batches ------------
__global__ __launch_bounds__(256) void aggregate_kernel(
    const ushort16* __restrict__ Tb, const float* __restrict__ dinv,
    const int* __restrict__ row_ptr, const int* __restrict__ csr,
    const float* __restrict__ bias, const float* __restrict__ gamma,
    const float* __restrict__ beta, const float* __restrict__ mean,
    const float* __restrict__ var,
    float* __restrict__ P, int N, int residual) {
    int node = (blockIdx.x * 256 + threadIdx.x) >> 6;
    int lane = threadIdx.x & 63;
    if (node >= N) return;
    int e = row_ptr[node], e1 = row_ptr[node + 1];
    float a0 = bf16_to_f32(Tb[(size_t)node * HDIM + lane]);  // self-loop term
    float a1 = 0.f, a2 = 0.f, a3 = 0.f;
    for (; e < e1; e += 16) {
        int4 s0 = *(const int4*)(csr + e);
        int4 s1 = *(const int4*)(csr + e + 4);
        int4 s2 = *(const int4*)(csr + e + 8);
        int4 s3 = *(const int4*)(csr + e + 12);
        float t0  = bf16_to_f32(Tb[(size_t)s0.x * HDIM + lane]);
        float t1  = bf16_to_f32(Tb[(size_t)s0.y * HDIM + lane]);
        float t2  = bf16_to_f32(Tb[(size_t)s0.z * HDIM + lane]);
        float t3  = bf16_to_f32(Tb[(size_t)s0.w * HDIM + lane]);
        float t4  = bf16_to_f32(Tb[(size_t)s1.x * HDIM + lane]);
        float t5  = bf16_to_f32(Tb[(size_t)s1.y * HDIM + lane]);
        float t6  = bf16_to_f32(Tb[(size_t)s1.z * HDIM + lane]);
        float t7  = bf16_to_f32(Tb[(size_t)s1.w * HDIM + lane]);
        float t8  = bf16_to_f32(Tb[(size_t)s2.x * HDIM + lane]);
        float t9  = bf16_to_f32(Tb[(size_t)s2.y * HDIM + lane]);
        float t10 = bf16_to_f32(Tb[(size_t)s2.z * HDIM + lane]);
        float t11 = bf16_to_f32(Tb[(size_t)s2.w * HDIM + lane]);
        float t12 = bf16_to_f32(Tb[(size_t)s3.x * HDIM + lane]);
        float t13 = bf16_to_f32(Tb[(size_t)s3.y * HDIM + lane]);
        float t14 = bf16_to_f32(Tb[(size_t)s3.z * HDIM + lane]);
        float t15 = bf16_to_f32(Tb[(size_t)s3.w * HDIM + lane]);
        a0 += t0 + t4;
        a1 += t1 + t5;
        a2 += t2 + t6;
        a3 += t3 + t7;
        a0 += t8 + t12;
        a1 += t9 + t13;
        a2 += t10 + t14;
        a3 += t11 + t15;
    }
    float acc = (a0 + a1) + (a2 + a3);
    float v = acc * dinv[node] + bias[lane];
    v = fmaxf(v, 0.f);
    v = (v - mean[lane]) * rsqrtf(var[lane] + 1e-5f) * gamma[lane] + beta[lane];
    if (residual) v += P[(size_t)node * HDIM + lane];
    P[(size_t)node * HDIM + lane] = v;
}

// ---------------- mean-pool ----------------
__global__ __launch_bounds__(256) void pool_kernel(const float* __restrict__ P,
                                                   const int* __restrict__ batch,
                                                   float* __restrict__ gsum,
                                                   float* __restrict__ gcnt, int N) {
    int wave = (blockIdx.x * 256 + threadIdx.x) >> 6;
    int lane = threadIdx.x & 63;
    int start = wave * 64;
    if (start >= N) return;
    int end = start + 64; if (end > N) end = N;
    float acc = 0.f;
    int cur = batch[start];
    int cnt = 0;
    for (int i = start; i < end; ++i) {
        int b = batch[i];
        if (b != cur) {
            atomicAdd(&gsum[cur * HDIM + lane], acc);
            if (lane == 0) atomicAdd(&gcnt[cur], (float)cnt);
            cur = b; acc = 0.f; cnt = 0;
        }
        acc += P[(size_t)i * HDIM + lane];
        cnt++;
    }
    atomicAdd(&gsum[cur * HDIM + lane], acc);
    if (lane == 0) atomicAdd(&gcnt[cur], (float)cnt);
}

// ---------------- MLP head (single block) ----------------
__global__ __launch_bounds__(256) void head_kernel(
    const float* __restrict__ gsum, const float* __restrict__ gcnt,
    const float* __restrict__ hW1, const float* __restrict__ hb1,
    const float* __restrict__ hgam, const float* __restrict__ hbet,
    const float* __restrict__ hm, const float* __restrict__ hv,
    const float* __restrict__ hW2, const float* __restrict__ hb2,
    float* __restrict__ out) {
    __shared__ float g[NGRAPH * HDIM];
    __shared__ float h1[NGRAPH * 32];
    int t = threadIdx.x;
    for (int idx = t; idx < NGRAPH * HDIM; idx += 256) {
        int gi = idx >> 6;
        g[idx] = gsum[idx] / fmaxf(gcnt[gi], 1.f);
    }
    __syncthreads();
    for (int idx = t; idx < NGRAPH * 32; idx += 256) {
        int gi = idx >> 5, j = idx & 31;
        float s = hb1[j];
#pragma unroll
        for (int f = 0; f < HDIM; ++f) s += g[gi * HDIM + f] * hW1[f * 32 + j];
        s = fmaxf(s, 0.f);
        s = (s - hm[j]) * rsqrtf(hv[j] + 1e-5f) * hgam[j] + hbet[j];
        h1[idx] = s;
    }
    __syncthreads();
    if (t < NGRAPH) {
        float s = hb2[0];
#pragma unroll
        for (int j = 0; j < 32; ++j) s += h1[t * 32 + j] * hW2[j];
        out[t] = s;
    }
}

static inline size_t align_up(size_t x) { return (x + 255) & ~(size_t)255; }

extern "C" void kernel_launch(void* const* d_in, const int* in_sizes, int n_in,
                              void* d_out, int out_size, void* d_ws, size_t ws_size,
                              hipStream_t stream) {
    const float* x    = (const float*)d_in[0];
    const int*   ei   = (const int*)d_in[1];
    const int*   batch= (const int*)d_in[2];
    const float* Wc   = (const float*)d_in[3];
    const float* bc   = (const float*)d_in[4];
    const float* bng  = (const float*)d_in[5];
    const float* bnb  = (const float*)d_in[6];
    const float* bnm  = (const float*)d_in[7];
    const float* bnv  = (const float*)d_in[8];
    const float* hW1  = (const float*)d_in[9];
    const float* hb1  = (const float*)d_in[10];
    const float* hgam = (const float*)d_in[11];
    const float* hbet = (const float*)d_in[12];
    const float* hm   = (const float*)d_in[13];
    const float* hv   = (const float*)d_in[14];
    const float* hW2  = (const float*)d_in[15];
    const float* hb2  = (const float*)d_in[16];
    float* out = (float*)d_out;

    const int N = in_sizes[0] / HDIM;   // 100000
    const int E = in_sizes[1] / 2;      // 1000000
    const int nbuck = (N + 255) >> 8;   // 391

    // ---- workspace carve (all 256B aligned) ----
    char* ws = (char*)d_ws;
    size_t off = 0;
    float*    P  = (float*)(ws + off);    off += align_up((size_t)N * HDIM * 4);
    ushort16* Tb = (ushort16*)(ws + off); off += align_up((size_t)(N + 1) * HDIM * 2); // +1 sentinel row
    int*   counts  = (int*)(ws + off);    off += align_up((size_t)N * 4);
    int*   row_ptr = (int*)(ws + off);    off += align_up((size_t)(N + 1) * 4);
    float* dinv    = (float*)(ws + off);  off += align_up((size_t)N * 4);
    int*   bsums   = (int*)(ws + off);    off += align_up(256 * 4);
    int*   bhist   = (int*)(ws + off);    off += align_up(512 * 4);
    int*   bbase   = (int*)(ws + off);    off += align_up(513 * 4);
    int*   bcursor = (int*)(ws + off);    off += align_up(512 * 4);
    // gsum | gcnt contiguous (zeroed together)
    float* gsum = (float*)(ws + off);
    float* gcnt = (float*)(ws + off + (size_t)NGRAPH * HDIM * 4);
    off += align_up((size_t)(NGRAPH * HDIM + NGRAPH) * 4);
    int2*  barr = (int2*)(ws + off);      off += align_up((size_t)E * 8);
    int*   csr  = (int*)(ws + off);       off += align_up(((size_t)E + (size_t)(PADM - 1) * N) * 4);

    int gN = (N + 255) / 256;
    int nScanBlocks = (N + SCAN_CHUNK - 1) / SCAN_CHUNK;   // 98
    int nPartBlocks = (E + EPB - 1) / EPB;                 // 245

    // ---- zero small state ----
    zero_kernel<<<2, 256, 0, stream>>>(bhist, nbuck);
    zero_kernel<<<(NGRAPH * HDIM + NGRAPH + 255) / 256, 256, 0, stream>>>((int*)gsum, NGRAPH * HDIM + NGRAPH);
    zero_kernel<<<1, 256, 0, stream>>>((int*)(Tb + (size_t)N * HDIM), 32);  // sentinel row = 0

    // ---- bucket partition + CSR build ----
    bucket_hist_kernel<<<nPartBlocks, 256, 0, stream>>>(ei, bhist, E, nbuck);
    bucket_scan_kernel<<<1, 512, 0, stream>>>(bhist, bbase, bcursor, nbuck);
    partition_kernel<<<nPartBlocks, 256, 0, stream>>>(ei, bcursor, barr, E, nbuck);
    degree_kernel<<<nbuck, 256, 0, stream>>>(barr, bbase, counts, N);
    bsum_kernel<<<nScanBlocks, 256, 0, stream>>>(counts, bsums, N);
    bscan_kernel<<<1, 256, 0, stream>>>(bsums, nScanBlocks, row_ptr, N);
    scan_apply_kernel<<<nScanBlocks, 256, 0, stream>>>(counts, bsums, row_ptr, dinv, N);
    fill_kernel<<<nbuck, 256, 0, stream>>>(barr, bbase, row_ptr, csr, N);

    // ---- 5 GCN layers ----
    int aggBlocks = (N + 3) / 4;
    for (int l = 0; l < 5; ++l) {
        const float* in = (l == 0) ? x : P;
        gemm64_kernel<<<gN, 256, 0, stream>>>(in, Wc + (size_t)l * HDIM * HDIM, dinv, Tb, N);
        aggregate_kernel<<<aggBlocks, 256, 0, stream>>>(
            Tb, dinv, row_ptr, csr,
            bc + l * HDIM, bng + l * HDIM, bnb + l * HDIM, bnm + l * HDIM, bnv + l * HDIM,
            P, N, (l > 0) ? 1 : 0);
    }

    // ---- pool + head ----
    int poolBlocks = (N + 255) / 256;
    pool_kernel<<<poolBlocks, 256, 0, stream>>>(P, batch, gsum, gcnt, N);
    head_kernel<<<1, 256, 0, stream>>>(gsum, gcnt, hW1, hb1, hgam, hbet, hm, hv, hW2, hb2, out);
}

// Round 7
// 480.826 us; speedup vs baseline: 1.4326x; 1.2161x over previous
//
#include <hip/hip_runtime.h>
#include <hip/hip_bf16.h>

// GCN: 5 x (GEMM 64x64 -> CSR gather + bias/ReLU/BN/residual) -> mean-pool -> MLP head.
// R2: hierarchical scan. R3: unrolled gather. R4: bf16 T. R5: norm folded into GEMM,
//     padded branch-free 16-wide gather. R6: 2-phase bucket-partition CSR build.
// R7: GEMM re-shaped: thread=(row,quarter), quarter=waveId (readfirstlane) ->
//     W loads are wave-uniform s_loads (SGPR), acc[16], 6252 waves (~76% occ)
//     vs R6's 1564 waves (14% occ).

#define NNODES 100000
#define NEDGES 1000000
#define NGRAPH 64
#define HDIM 64
#define SCAN_CHUNK 1024
#define PADM 16      // bucket pad multiple for aggregate's 16-wide batches
#define EPB 4096     // edges per block in partition phases

typedef unsigned int uint32;
typedef unsigned short ushort16;

__device__ __forceinline__ float bf16_to_f32(ushort16 u) {
    return __uint_as_float(((uint32)u) << 16);
}
__device__ __forceinline__ uint32 pack_bf16x2(float lo, float hi) {
    __hip_bfloat16 l = __float2bfloat16(lo);
    __hip_bfloat16 h = __float2bfloat16(hi);
    return ((uint32)(*(ushort16*)&h) << 16) | (uint32)(*(ushort16*)&l);
}
__device__ __forceinline__ int padded(int c) { return (c + PADM - 1) & ~(PADM - 1); }

// ---------------- zero ----------------
__global__ void zero_kernel(int* __restrict__ p, int n) {
    int i = blockIdx.x * 256 + threadIdx.x;
    if (i < n) p[i] = 0;
}

// ---------------- A1: bucket histogram (bucket = dst>>8) ----------------
__global__ __launch_bounds__(256) void bucket_hist_kernel(const int* __restrict__ ei,
                                                          int* __restrict__ bhist,
                                                          int E, int nbuck) {
    __shared__ int h[512];
    for (int i = threadIdx.x; i < nbuck; i += 256) h[i] = 0;
    __syncthreads();
    int base = blockIdx.x * EPB;
    int end = base + EPB; if (end > E) end = E;
    for (int e = base + threadIdx.x; e < end; e += 256)
        atomicAdd(&h[ei[E + e] >> 8], 1);
    __syncthreads();
    for (int i = threadIdx.x; i < nbuck; i += 256)
        if (h[i]) atomicAdd(&bhist[i], h[i]);
}

// ---------------- bucket scan: bases + cursors ----------------
__global__ __launch_bounds__(512) void bucket_scan_kernel(const int* __restrict__ bhist,
                                                          int* __restrict__ bbase,
                                                          int* __restrict__ bcursor,
                                                          int nbuck) {
    __shared__ int sh[512];
    int t = threadIdx.x;
    sh[t] = (t < nbuck) ? bhist[t] : 0;
    __syncthreads();
    for (int off = 1; off < 512; off <<= 1) {
        int v = (t >= off) ? sh[t - off] : 0;
        __syncthreads();
        sh[t] += v;
        __syncthreads();
    }
    int ex = (t == 0) ? 0 : sh[t - 1];
    if (t < nbuck) { bbase[t] = ex; bcursor[t] = ex; }
    if (t == nbuck) bbase[t] = sh[nbuck - 1];   // = E
}

// ---------------- A2: partition edges into bucket-contiguous (src,dst) ----------------
__global__ __launch_bounds__(256) void partition_kernel(const int* __restrict__ ei,
                                                        int* __restrict__ bcursor,
                                                        int2* __restrict__ barr,
                                                        int E, int nbuck) {
    __shared__ int h[512];
    __shared__ int lbase[512];
    for (int i = threadIdx.x; i < nbuck; i += 256) h[i] = 0;
    __syncthreads();
    int base = blockIdx.x * EPB;
    int end = base + EPB; if (end > E) end = E;
    for (int e = base + threadIdx.x; e < end; e += 256)
        atomicAdd(&h[ei[E + e] >> 8], 1);
    __syncthreads();
    for (int i = threadIdx.x; i < nbuck; i += 256) {
        int c = h[i];
        lbase[i] = c ? atomicAdd(&bcursor[i], c) : 0;
        h[i] = 0;   // reuse as local cursor
    }
    __syncthreads();
    for (int e = base + threadIdx.x; e < end; e += 256) {
        int s = ei[e];
        int d = ei[E + e];
        int b = d >> 8;
        int r = atomicAdd(&h[b], 1);
        barr[lbase[b] + r] = make_int2(s, d);
    }
}

// ---------------- B0: per-bucket node degrees (dense write, LDS hist) ------------------
__global__ __launch_bounds__(256) void degree_kernel(const int2* __restrict__ barr,
                                                     const int* __restrict__ bbase,
                                                     int* __restrict__ counts, int N) {
    __shared__ int h[256];
    h[threadIdx.x] = 0;
    __syncthreads();
    int b = blockIdx.x;
    int s0 = bbase[b], s1 = bbase[b + 1];
    for (int e = s0 + threadIdx.x; e < s1; e += 256)
        atomicAdd(&h[barr[e].y & 255], 1);
    __syncthreads();
    int node = (b << 8) + threadIdx.x;
    if (node < N) counts[node] = h[threadIdx.x];
}

// ---------------- scan level 1: per-block partial sums of PADDED counts ---------------
__global__ __launch_bounds__(256) void bsum_kernel(const int* __restrict__ counts,
                                                   int* __restrict__ bsums, int N) {
    __shared__ int ws[4];
    int base = blockIdx.x * SCAN_CHUNK + threadIdx.x * 4;
    int s = 0;
    if (base + 3 < N) {
        int4 c = *(const int4*)(counts + base);
        s = padded(c.x) + padded(c.y) + padded(c.z) + padded(c.w);
    } else {
        for (int k = 0; k < 4 && base + k < N; ++k) s += padded(counts[base + k]);
    }
    for (int off = 32; off > 0; off >>= 1) s += __shfl_down(s, off, 64);
    int wid = threadIdx.x >> 6;
    if ((threadIdx.x & 63) == 0) ws[wid] = s;
    __syncthreads();
    if (threadIdx.x == 0) bsums[blockIdx.x] = ws[0] + ws[1] + ws[2] + ws[3];
}

// ---------------- scan level 2 ----------------
__global__ __launch_bounds__(256) void bscan_kernel(int* __restrict__ bsums, int nb,
                                                    int* __restrict__ row_ptr, int N) {
    __shared__ int sh[256];
    int t = threadIdx.x;
    sh[t] = (t < nb) ? bsums[t] : 0;
    __syncthreads();
    for (int off = 1; off < 256; off <<= 1) {
        int v = (t >= off) ? sh[t - off] : 0;
        __syncthreads();
        sh[t] += v;
        __syncthreads();
    }
    if (t < nb) bsums[t] = (t == 0) ? 0 : sh[t - 1];
    if (t == 255) row_ptr[N] = sh[255];   // total padded entries
}

// ---------------- scan level 3: row_ptr (padded) + dinv ----------------
__global__ __launch_bounds__(256) void scan_apply_kernel(
    const int* __restrict__ counts, const int* __restrict__ bsums,
    int* __restrict__ row_ptr, float* __restrict__ dinv, int N) {
    __shared__ int wsum[4];
    int t = threadIdx.x;
    int lane = t & 63, wid = t >> 6;
    int base = blockIdx.x * SCAN_CHUNK + t * 4;
    int c0 = 0, c1 = 0, c2 = 0, c3 = 0;
    if (base + 3 < N) {
        int4 c = *(const int4*)(counts + base);
        c0 = c.x; c1 = c.y; c2 = c.z; c3 = c.w;
    } else if (base < N) {
        c0 = counts[base];
        if (base + 1 < N) c1 = counts[base + 1];
        if (base + 2 < N) c2 = counts[base + 2];
    }
    int p0 = padded(c0), p1 = padded(c1), p2 = padded(c2), p3 = padded(c3);
    int tsum = p0 + p1 + p2 + p3;
    int incl = tsum;
    for (int off = 1; off < 64; off <<= 1) {
        int v = __shfl_up(incl, off, 64);
        if (lane >= off) incl += v;
    }
    if (lane == 63) wsum[wid] = incl;
    __syncthreads();
    int woff = 0;
    for (int w = 0; w < wid; ++w) woff += wsum[w];
    int off0 = bsums[blockIdx.x] + woff + (incl - tsum);
    if (base + 3 < N) {
        int4 rp; rp.x = off0; rp.y = off0 + p0; rp.z = off0 + p0 + p1; rp.w = off0 + p0 + p1 + p2;
        *(int4*)(row_ptr + base) = rp;
        float4 dv;
        dv.x = rsqrtf((float)(c0 + 1)); dv.y = rsqrtf((float)(c1 + 1));
        dv.z = rsqrtf((float)(c2 + 1)); dv.w = rsqrtf((float)(c3 + 1));
        *(float4*)(dinv + base) = dv;
    } else if (base < N) {
        int run = off0;
        int cs[4] = {c0, c1, c2, c3};
        for (int k = 0; k < 4 && base + k < N; ++k) {
            row_ptr[base + k] = run;
            dinv[base + k] = rsqrtf((float)(cs[k] + 1));
            run += padded(cs[k]);
        }
    }
}

// ---------------- B1: per-bucket counting-sort into csr + sentinel padding -------------
__global__ __launch_bounds__(256) void fill_kernel(const int2* __restrict__ barr,
                                                   const int* __restrict__ bbase,
                                                   const int* __restrict__ row_ptr,
                                                   int* __restrict__ csr, int N) {
    __shared__ int rbase[257];
    __shared__ int cur[256];
    int b = blockIdx.x;
    int n0 = b << 8;
    int nn = N - n0; if (nn > 256) nn = 256;
    int t = threadIdx.x;
    if (t < nn) { rbase[t] = row_ptr[n0 + t]; cur[t] = 0; }
    if (t == 0) rbase[nn] = row_ptr[n0 + nn];
    __syncthreads();
    int s0 = bbase[b], s1 = bbase[b + 1];
    for (int e = s0 + t; e < s1; e += 256) {
        int2 ed = barr[e];
        int d = ed.y & 255;
        int r = atomicAdd(&cur[d], 1);
        csr[rbase[d] + r] = ed.x;
    }
    __syncthreads();
    if (t < nn) {
        int p = rbase[t] + cur[t];
        int pe = rbase[t + 1];
        for (; p < pe; ++p) csr[p] = N;   // sentinel -> zero row Tb[N]
    }
}

// ------- GEMM: T'(bf16) = dinv[row] * (A @ W); thread=(row, quarter=waveId) ------------
// 64 rows/block, wave q computes cols [q*16, q*16+16). W addrs wave-uniform -> s_load.
__global__ __launch_bounds__(256) void gemm64_kernel(const float* __restrict__ A,
                                                     const float* __restrict__ W,
                                                     const float* __restrict__ dinv,
                                                     ushort16* __restrict__ Tb, int N) {
    int lane = threadIdx.x & 63;
    int q = __builtin_amdgcn_readfirstlane(threadIdx.x >> 6);   // wave-uniform quarter
    int row = blockIdx.x * 64 + lane;
    if (row >= N) return;
    const float4* arow = (const float4*)(A + (size_t)row * HDIM);
    const float* Wq = W + q * 16;
    float acc[16];
#pragma unroll
    for (int j = 0; j < 16; ++j) acc[j] = 0.f;
#pragma unroll 4
    for (int k4 = 0; k4 < 16; ++k4) {
        float4 a4 = arow[k4];
        const float* w0 = Wq + (k4 * 4) * HDIM;
#pragma unroll
        for (int j = 0; j < 16; ++j) acc[j] = fmaf(a4.x, w0[j], acc[j]);
#pragma unroll
        for (int j = 0; j < 16; ++j) acc[j] = fmaf(a4.y, w0[HDIM + j], acc[j]);
#pragma unroll
        for (int j = 0; j < 16; ++j) acc[j] = fmaf(a4.z, w0[2 * HDIM + j], acc[j]);
#pragma unroll
        for (int j = 0; j < 16; ++j) acc[j] = fmaf(a4.w, w0[3 * HDIM + j], acc[j]);
    }
    float di = dinv[row];
    uint4 o0, o1;
    o0.x = pack_bf16x2(acc[0] * di,  acc[1] * di);
    o0.y = pack_bf16x2(acc[2] * di,  acc[3] * di);
    o0.z = pack_bf16x2(acc[4] * di,  acc[5] * di);
    o0.w = pack_bf16x2(acc[6] * di,  acc[7] * di);
    o1.x = pack_bf16x2(acc[8] * di,  acc[9] * di);
    o1.y = pack_bf16x2(acc[10] * di, acc[11] * di);
    o1.z = pack_bf16x2(acc[12] * di, acc[13] * di);
    o1.w = pack_bf16x2(acc[14] * di, acc[15] * di);
    uint4* orow = (uint4*)(Tb + (size_t)row * HDIM + q * 16);
    orow[0] = o0;
    orow[1] = o1;
}

// ------- gather(bf16) + bias/ReLU/BN/residual: 16-wide branch-free batches ------------
__global__ __launch_bounds__(256) void aggregate_kernel(
    const ushort16* __restrict__ Tb, const float* __restrict__ dinv,
    const int* __restrict__ row_ptr, const int* __restrict__ csr,
    const float* __restrict__ bias, const float* __restrict__ gamma,
    const float* __restrict__ beta, const float* __restrict__ mean,
    const float* __restrict__ var,
    float* __restrict__ P, int N, int residual) {
    int node = (blockIdx.x * 256 + threadIdx.x) >> 6;
    int lane = threadIdx.x & 63;
    if (node >= N) return;
    int e = row_ptr[node], e1 = row_ptr[node + 1];
    float a0 = bf16_to_f32(Tb[(size_t)node * HDIM + lane]);  // self-loop term
    float a1 = 0.f, a2 = 0.f, a3 = 0.f;
    for (; e < e1; e += 16) {
        int4 s0 = *(const int4*)(csr + e);
        int4 s1 = *(const int4*)(csr + e + 4);
        int4 s2 = *(const int4*)(csr + e + 8);
        int4 s3 = *(const int4*)(csr + e + 12);
        float t0  = bf16_to_f32(Tb[(size_t)s0.x * HDIM + lane]);
        float t1  = bf16_to_f32(Tb[(size_t)s0.y * HDIM + lane]);
        float t2  = bf16_to_f32(Tb[(size_t)s0.z * HDIM + lane]);
        float t3  = bf16_to_f32(Tb[(size_t)s0.w * HDIM + lane]);
        float t4  = bf16_to_f32(Tb[(size_t)s1.x * HDIM + lane]);
        float t5  = bf16_to_f32(Tb[(size_t)s1.y * HDIM + lane]);
        float t6  = bf16_to_f32(Tb[(size_t)s1.z * HDIM + lane]);
        float t7  = bf16_to_f32(Tb[(size_t)s1.w * HDIM + lane]);
        float t8  = bf16_to_f32(Tb[(size_t)s2.x * HDIM + lane]);
        float t9  = bf16_to_f32(Tb[(size_t)s2.y * HDIM + lane]);
        float t10 = bf16_to_f32(Tb[(size_t)s2.z * HDIM + lane]);
        float t11 = bf16_to_f32(Tb[(size_t)s2.w * HDIM + lane]);
        float t12 = bf16_to_f32(Tb[(size_t)s3.x * HDIM + lane]);
        float t13 = bf16_to_f32(Tb[(size_t)s3.y * HDIM + lane]);
        float t14 = bf16_to_f32(Tb[(size_t)s3.z * HDIM + lane]);
        float t15 = bf16_to_f32(Tb[(size_t)s3.w * HDIM + lane]);
        a0 += t0 + t4;
        a1 += t1 + t5;
        a2 += t2 + t6;
        a3 += t3 + t7;
        a0 += t8 + t12;
        a1 += t9 + t13;
        a2 += t10 + t14;
        a3 += t11 + t15;
    }
    float acc = (a0 + a1) + (a2 + a3);
    float v = acc * dinv[node] + bias[lane];
    v = fmaxf(v, 0.f);
    v = (v - mean[lane]) * rsqrtf(var[lane] + 1e-5f) * gamma[lane] + beta[lane];
    if (residual) v += P[(size_t)node * HDIM + lane];
    P[(size_t)node * HDIM + lane] = v;
}

// ---------------- mean-pool ----------------
__global__ __launch_bounds__(256) void pool_kernel(const float* __restrict__ P,
                                                   const int* __restrict__ batch,
                                                   float* __restrict__ gsum,
                                                   float* __restrict__ gcnt, int N) {
    int wave = (blockIdx.x * 256 + threadIdx.x) >> 6;
    int lane = threadIdx.x & 63;
    int start = wave * 64;
    if (start >= N) return;
    int end = start + 64; if (end > N) end = N;
    float acc = 0.f;
    int cur = batch[start];
    int cnt = 0;
    for (int i = start; i < end; ++i) {
        int b = batch[i];
        if (b != cur) {
            atomicAdd(&gsum[cur * HDIM + lane], acc);
            if (lane == 0) atomicAdd(&gcnt[cur], (float)cnt);
            cur = b; acc = 0.f; cnt = 0;
        }
        acc += P[(size_t)i * HDIM + lane];
        cnt++;
    }
    atomicAdd(&gsum[cur * HDIM + lane], acc);
    if (lane == 0) atomicAdd(&gcnt[cur], (float)cnt);
}

// ---------------- MLP head (single block) ----------------
__global__ __launch_bounds__(256) void head_kernel(
    const float* __restrict__ gsum, const float* __restrict__ gcnt,
    const float* __restrict__ hW1, const float* __restrict__ hb1,
    const float* __restrict__ hgam, const float* __restrict__ hbet,
    const float* __restrict__ hm, const float* __restrict__ hv,
    const float* __restrict__ hW2, const float* __restrict__ hb2,
    float* __restrict__ out) {
    __shared__ float g[NGRAPH * HDIM];
    __shared__ float h1[NGRAPH * 32];
    int t = threadIdx.x;
    for (int idx = t; idx < NGRAPH * HDIM; idx += 256) {
        int gi = idx >> 6;
        g[idx] = gsum[idx] / fmaxf(gcnt[gi], 1.f);
    }
    __syncthreads();
    for (int idx = t; idx < NGRAPH * 32; idx += 256) {
        int gi = idx >> 5, j = idx & 31;
        float s = hb1[j];
#pragma unroll
        for (int f = 0; f < HDIM; ++f) s += g[gi * HDIM + f] * hW1[f * 32 + j];
        s = fmaxf(s, 0.f);
        s = (s - hm[j]) * rsqrtf(hv[j] + 1e-5f) * hgam[j] + hbet[j];
        h1[idx] = s;
    }
    __syncthreads();
    if (t < NGRAPH) {
        float s = hb2[0];
#pragma unroll
        for (int j = 0; j < 32; ++j) s += h1[t * 32 + j] * hW2[j];
        out[t] = s;
    }
}

static inline size_t align_up(size_t x) { return (x + 255) & ~(size_t)255; }

extern "C" void kernel_launch(void* const* d_in, const int* in_sizes, int n_in,
                              void* d_out, int out_size, void* d_ws, size_t ws_size,
                              hipStream_t stream) {
    const float* x    = (const float*)d_in[0];
    const int*   ei   = (const int*)d_in[1];
    const int*   batch= (const int*)d_in[2];
    const float* Wc   = (const float*)d_in[3];
    const float* bc   = (const float*)d_in[4];
    const float* bng  = (const float*)d_in[5];
    const float* bnb  = (const float*)d_in[6];
    const float* bnm  = (const float*)d_in[7];
    const float* bnv  = (const float*)d_in[8];
    const float* hW1  = (const float*)d_in[9];
    const float* hb1  = (const float*)d_in[10];
    const float* hgam = (const float*)d_in[11];
    const float* hbet = (const float*)d_in[12];
    const float* hm   = (const float*)d_in[13];
    const float* hv   = (const float*)d_in[14];
    const float* hW2  = (const float*)d_in[15];
    const float* hb2  = (const float*)d_in[16];
    float* out = (float*)d_out;

    const int N = in_sizes[0] / HDIM;   // 100000
    const int E = in_sizes[1] / 2;      // 1000000
    const int nbuck = (N + 255) >> 8;   // 391

    // ---- workspace carve (all 256B aligned) ----
    char* ws = (char*)d_ws;
    size_t off = 0;
    float*    P  = (float*)(ws + off);    off += align_up((size_t)N * HDIM * 4);
    ushort16* Tb = (ushort16*)(ws + off); off += align_up((size_t)(N + 1) * HDIM * 2); // +1 sentinel row
    int*   counts  = (int*)(ws + off);    off += align_up((size_t)N * 4);
    int*   row_ptr = (int*)(ws + off);    off += align_up((size_t)(N + 1) * 4);
    float* dinv    = (float*)(ws + off);  off += align_up((size_t)N * 4);
    int*   bsums   = (int*)(ws + off);    off += align_up(256 * 4);
    int*   bhist   = (int*)(ws + off);    off += align_up(512 * 4);
    int*   bbase   = (int*)(ws + off);    off += align_up(513 * 4);
    int*   bcursor = (int*)(ws + off);    off += align_up(512 * 4);
    float* gsum = (float*)(ws + off);
    float* gcnt = (float*)(ws + off + (size_t)NGRAPH * HDIM * 4);
    off += align_up((size_t)(NGRAPH * HDIM + NGRAPH) * 4);
    int2*  barr = (int2*)(ws + off);      off += align_up((size_t)E * 8);
    int*   csr  = (int*)(ws + off);       off += align_up(((size_t)E + (size_t)(PADM - 1) * N) * 4);

    int nScanBlocks = (N + SCAN_CHUNK - 1) / SCAN_CHUNK;   // 98
    int nPartBlocks = (E + EPB - 1) / EPB;                 // 245
    int gemmBlocks  = (N + 63) / 64;                       // 1563

    // ---- zero small state ----
    zero_kernel<<<2, 256, 0, stream>>>(bhist, nbuck);
    zero_kernel<<<(NGRAPH * HDIM + NGRAPH + 255) / 256, 256, 0, stream>>>((int*)gsum, NGRAPH * HDIM + NGRAPH);
    zero_kernel<<<1, 256, 0, stream>>>((int*)(Tb + (size_t)N * HDIM), 32);  // sentinel row = 0

    // ---- bucket partition + CSR build ----
    bucket_hist_kernel<<<nPartBlocks, 256, 0, stream>>>(ei, bhist, E, nbuck);
    bucket_scan_kernel<<<1, 512, 0, stream>>>(bhist, bbase, bcursor, nbuck);
    partition_kernel<<<nPartBlocks, 256, 0, stream>>>(ei, bcursor, barr, E, nbuck);
    degree_kernel<<<nbuck, 256, 0, stream>>>(barr, bbase, counts, N);
    bsum_kernel<<<nScanBlocks, 256, 0, stream>>>(counts, bsums, N);
    bscan_kernel<<<1, 256, 0, stream>>>(bsums, nScanBlocks, row_ptr, N);
    scan_apply_kernel<<<nScanBlocks, 256, 0, stream>>>(counts, bsums, row_ptr, dinv, N);
    fill_kernel<<<nbuck, 256, 0, stream>>>(barr, bbase, row_ptr, csr, N);

    // ---- 5 GCN layers ----
    int aggBlocks = (N + 3) / 4;
    for (int l = 0; l < 5; ++l) {
        const float* in = (l == 0) ? x : P;
        gemm64_kernel<<<gemmBlocks, 256, 0, stream>>>(in, Wc + (size_t)l * HDIM * HDIM, dinv, Tb, N);
        aggregate_kernel<<<aggBlocks, 256, 0, stream>>>(
            Tb, dinv, row_ptr, csr,
            bc + l * HDIM, bng + l * HDIM, bnb + l * HDIM, bnm + l * HDIM, bnv + l * HDIM,
            P, N, (l > 0) ? 1 : 0);
    }

    // ---- pool + head ----
    int poolBlocks = (N + 255) / 256;
    pool_kernel<<<poolBlocks, 256, 0, stream>>>(P, batch, gsum, gcnt, N);
    head_kernel<<<1, 256, 0, stream>>>(gsum, gcnt, hW1, hb1, hgam, hbet, hm, hv, hW2, hb2, out);
}